// Round 5
// baseline (83.263 us; speedup 1.0000x reference)
//
#include <hip/hip_runtime.h>
#include <hip/hip_bf16.h>
#include <cstdint>
#include <cstddef>

#define NUM_CLASS 1000
#define NPAD      1024
#define LOW_DIM   128
#define B_UPD     1024
#define B_SIM     65536

typedef short bf16x8 __attribute__((ext_vector_type(8)));
typedef float f32x4  __attribute__((ext_vector_type(4)));

__device__ __forceinline__ unsigned short f2bf(float f) {
  union { float f; unsigned u; } a; a.f = f;
  unsigned u = a.u;
  return (unsigned short)((u + 0x7fffu + ((u >> 16) & 1u)) >> 16);  // RNE
}

// ---------- kernel 1: per-class EMA (ballot scan) + L2 norm -> fragment-swizzled bf16 ----------
// Updates to different labels commute, so per-class in-order processing
// reproduces the reference lax.scan exactly.
// Output layout = MFMA B-fragment order:
//   slot[((g*4 + kk)*64 + l) * 8 + e]  (ushort units)
//   holds logical B[row = g*16 + (l&15)][k = kk*32 + (l>>4)*8 + e]
__global__ void proto_update_kernel(const float* __restrict__ pred_feat,
                                    const int*   __restrict__ labels,
                                    const float* __restrict__ protos_in,
                                    unsigned short* __restrict__ protos_sw) {
  int c = blockIdx.x;    // 0..1023
  int d = threadIdx.x;   // 0..127
  float p = 0.0f;
  if (c < NUM_CLASS) {
    p = protos_in[c * LOW_DIM + d];
    #pragma unroll 4
    for (int k = 0; k < B_UPD / 64; ++k) {
      int lab = labels[k * 64 + (d & 63)];
      unsigned long long m = __ballot(lab == c);   // wave-uniform
      while (m) {
        int b = __builtin_ctzll(m);
        m &= (m - 1);
        p = 0.99f * p + 0.01f * pred_feat[(size_t)(k * 64 + b) * LOW_DIM + d];
      }
    }
  }
  float sq = p * p;
  #pragma unroll
  for (int o = 1; o < 64; o <<= 1) sq += __shfl_xor(sq, o, 64);
  __shared__ float wsum[2];
  if ((d & 63) == 0) wsum[d >> 6] = sq;
  __syncthreads();
  float total = wsum[0] + wsum[1];
  unsigned short v = f2bf(p / fmaxf(sqrtf(total), 1e-12f));  // c>=1000 -> 0
  int g = c >> 4, r = c & 15, kk = d >> 5, j = (d >> 3) & 3, e = d & 7;
  protos_sw[(size_t)((g * 4 + kk) * 64 + j * 16 + r) * 8 + e] = v;
}

// ---------- kernel 2: C = A(f32->bf16) @ B^T, streaming-store strips ----------
// TPB=256 (4 waves), BM=32, full N per block. Wave w owns 32 rows x cols
// [w*256, w*256+256), processed as 4 strips of 64 cols: compute acc[2][4]
// (32 VGPR) -> per-wave LDS transpose (16x68, uniform bank spread) -> 256-B
// f32x4 store segments, issued INSIDE the loop so the write stream is steady
// instead of one end-of-block burst. VGPR ~<=102 -> 5 blocks/CU, LDS 25.4 KB.
#define BM      32
#define TPB2    256
#define TSTRIDE 68      // f32 stride of transpose buffer (64+4)

__global__ __launch_bounds__(TPB2, 5)
void gemm_sim_kernel(const float* __restrict__ A,
                     const unsigned short* __restrict__ Bsw,
                     float* __restrict__ C) {
  __shared__ alignas(16) unsigned char Als[BM * 256];          // 8 KB swizzled A
  __shared__ alignas(16) float Tbuf[4][16 * TSTRIDE];          // 17.4 KB
  int t  = threadIdx.x;
  int m0 = blockIdx.x * BM;

  // ---- stage A: 32 rows x 128 f32 -> bf16, XOR-swizzled (rows 256 B) ----
  #pragma unroll
  for (int it = 0; it < 2; ++it) {
    int idx = it * TPB2 + t;
    int row = idx >> 4, c8 = idx & 15;
    const float4* s = reinterpret_cast<const float4*>(A + (size_t)(m0 + row) * LOW_DIM + c8 * 8);
    float4 v0 = s[0], v1 = s[1];
    uint4 q;
    q.x = f2bf(v0.x) | ((unsigned)f2bf(v0.y) << 16);
    q.y = f2bf(v0.z) | ((unsigned)f2bf(v0.w) << 16);
    q.z = f2bf(v1.x) | ((unsigned)f2bf(v1.y) << 16);
    q.w = f2bf(v1.z) | ((unsigned)f2bf(v1.w) << 16);
    *reinterpret_cast<uint4*>(Als + row * 256 + ((c8 * 16) ^ ((row & 7) << 4))) = q;
  }
  __syncthreads();

  int lane = t & 63;
  int w    = t >> 6;
  int lr   = lane & 15;
  int lkb  = (lane >> 4) * 16;
  float* myT = Tbuf[w];

  #pragma unroll
  for (int s = 0; s < 4; ++s) {                // 4 strips of 64 cols
    int gbase = w * 16 + s * 4;                // first 16-row B group of strip
    f32x4 acc[2][4];
    #pragma unroll
    for (int m = 0; m < 2; ++m)
      #pragma unroll
      for (int n = 0; n < 4; ++n)
        acc[m][n] = (f32x4){0.f, 0.f, 0.f, 0.f};

    #pragma unroll
    for (int kk = 0; kk < 4; ++kk) {           // K = 4 x 32
      int kb = kk * 64 + lkb;
      bf16x8 af[2];
      #pragma unroll
      for (int m = 0; m < 2; ++m) {
        int row = m * 16 + lr;
        af[m] = *reinterpret_cast<const bf16x8*>(Als + row * 256 + (kb ^ ((row & 7) << 4)));
      }
      #pragma unroll
      for (int n = 0; n < 4; ++n) {
        bf16x8 bf = *reinterpret_cast<const bf16x8*>(
            Bsw + ((size_t)((gbase + n) * 4 + kk) * 64 + lane) * 8);  // 1KB/wave coalesced
        #pragma unroll
        for (int m = 0; m < 2; ++m)
          acc[m][n] = __builtin_amdgcn_mfma_f32_16x16x32_bf16(af[m], bf, acc[m][n], 0, 0, 0);
      }
    }

    // ---- per-wave transpose + streaming stores (wave-local, in-order DS) ----
    int wc = gbase * 16;                       // strip col base
    #pragma unroll
    for (int m = 0; m < 2; ++m) {
      int rbase = (lane >> 4) * 4;
      #pragma unroll
      for (int n = 0; n < 4; ++n)
        #pragma unroll
        for (int r = 0; r < 4; ++r)
          myT[(rbase + r) * TSTRIDE + n * 16 + lr] = acc[m][n][r];
      #pragma unroll
      for (int it = 0; it < 4; ++it) {
        int idx = it * 64 + lane;
        int row = idx >> 4;                    // 0..15
        int c4  = idx & 15;                    // f32x4 chunk within 64 cols
        f32x4 v = *reinterpret_cast<const f32x4*>(myT + row * TSTRIDE + c4 * 4);
        int col = wc + c4 * 4;
        if (col < NUM_CLASS) {                 // 1000 % 4 == 0, clean mask
          *reinterpret_cast<f32x4*>(C + (size_t)(m0 + m * 16 + row) * NUM_CLASS + col) = v;
        }
      }
    }
  }
}

extern "C" void kernel_launch(void* const* d_in, const int* in_sizes, int n_in,
                              void* d_out, int out_size, void* d_ws, size_t ws_size,
                              hipStream_t stream) {
  const float* pred_feat = (const float*)d_in[0];   // [1024,128]
  const int*   labels    = (const int*)d_in[1];     // [1024]
  const float* protos    = (const float*)d_in[2];   // [1000,128]
  const float* feat      = (const float*)d_in[3];   // [65536,128]
  float* out = (float*)d_out;                       // [65536,1000]

  unsigned short* protos_sw = (unsigned short*)d_ws;  // 256 KB fragment-swizzled

  proto_update_kernel<<<NPAD, 128, 0, stream>>>(pred_feat, labels, protos, protos_sw);
  gemm_sim_kernel<<<B_SIM / BM, TPB2, 0, stream>>>(feat, protos_sw, out);
}

// Round 6
// 73.878 us; speedup vs baseline: 1.1270x; 1.1270x over previous
//
#include <hip/hip_runtime.h>
#include <hip/hip_bf16.h>
#include <cstdint>
#include <cstddef>

#define NUM_CLASS 1000
#define NPAD      1024
#define LOW_DIM   128
#define B_UPD     1024
#define B_SIM     65536

typedef short bf16x8 __attribute__((ext_vector_type(8)));
typedef float f32x4  __attribute__((ext_vector_type(4)));

__device__ __forceinline__ unsigned short f2bf(float f) {
  union { float f; unsigned u; } a; a.f = f;
  unsigned u = a.u;
  return (unsigned short)((u + 0x7fffu + ((u >> 16) & 1u)) >> 16);  // RNE
}

// ---------- kernel 1: per-class EMA (ballot scan) + L2 norm -> fragment-swizzled bf16 ----------
// Updates to different labels commute, so per-class in-order processing
// reproduces the reference lax.scan exactly.
// Output layout = MFMA B-fragment order so GEMM B loads are coalesced 1KB
// wave reads:
//   slot[((g*4 + kk)*64 + l) * 8 + e]  (ushort units)
//   holds logical B[row = g*16 + (l&15)][k = kk*32 + (l>>4)*8 + e]
__global__ void proto_update_kernel(const float* __restrict__ pred_feat,
                                    const int*   __restrict__ labels,
                                    const float* __restrict__ protos_in,
                                    unsigned short* __restrict__ protos_sw) {
  int c = blockIdx.x;    // 0..1023
  int d = threadIdx.x;   // 0..127
  float p = 0.0f;
  if (c < NUM_CLASS) {
    p = protos_in[c * LOW_DIM + d];
    #pragma unroll 4
    for (int k = 0; k < B_UPD / 64; ++k) {
      int lab = labels[k * 64 + (d & 63)];
      unsigned long long m = __ballot(lab == c);   // wave-uniform
      while (m) {
        int b = __builtin_ctzll(m);
        m &= (m - 1);
        p = 0.99f * p + 0.01f * pred_feat[(size_t)(k * 64 + b) * LOW_DIM + d];
      }
    }
  }
  float sq = p * p;
  #pragma unroll
  for (int o = 1; o < 64; o <<= 1) sq += __shfl_xor(sq, o, 64);
  __shared__ float wsum[2];
  if ((d & 63) == 0) wsum[d >> 6] = sq;
  __syncthreads();
  float total = wsum[0] + wsum[1];
  unsigned short v = f2bf(p / fmaxf(sqrtf(total), 1e-12f));  // c>=1000 -> 0
  int g = c >> 4, r = c & 15, kk = d >> 5, j = (d >> 3) & 3, e = d & 7;
  protos_sw[(size_t)((g * 4 + kk) * 64 + j * 16 + r) * 8 + e] = v;
}

// ---------- kernel 2: C[65536,1000] = A(f32->bf16) @ B^T, BM=32 x full-N ----------
// R4 structure (best measured: 74.2 us total) with the staging bug fixed:
// stage exactly BM=32 rows (was 64 -> 2x A fetch + OOB read on last block).
// 8 waves; wave w owns 32 rows x cols [w*128, w*128+128). acc[2][8]=64 VGPR,
// launch_bounds(512,4) -> 2 blocks/CU (LDS 67.6 KB): one block's stage/MFMA
// hides under the other's store drain.
#define BM   32
#define TPB2 512
#define CPAD 132                 // epilogue f32 LDS row stride (128+4)
#define EPW  (16 * CPAD)         // floats per wave epilogue region (8448 B)

__global__ __launch_bounds__(TPB2, 4)
void gemm_sim_kernel(const float* __restrict__ A,
                     const unsigned short* __restrict__ Bsw,
                     float* __restrict__ C) {
  __shared__ unsigned char smem[8 * EPW * 4];   // 67584 B (union: 8KB A-tile / epilogue)
  int t  = threadIdx.x;
  int m0 = blockIdx.x * BM;

  // ---- stage A: exactly 32 rows x 128 f32 -> bf16, XOR-swizzled (rows 256 B) ----
  {
    int row = t >> 4, c8 = t & 15;   // 512 threads = 32 rows x 16 slots
    const float4* s = reinterpret_cast<const float4*>(A + (size_t)(m0 + row) * LOW_DIM + c8 * 8);
    float4 v0 = s[0], v1 = s[1];
    uint4 q;
    q.x = f2bf(v0.x) | ((unsigned)f2bf(v0.y) << 16);
    q.y = f2bf(v0.z) | ((unsigned)f2bf(v0.w) << 16);
    q.z = f2bf(v1.x) | ((unsigned)f2bf(v1.y) << 16);
    q.w = f2bf(v1.z) | ((unsigned)f2bf(v1.w) << 16);
    *reinterpret_cast<uint4*>(smem + row * 256 + ((c8 * 16) ^ ((row & 7) << 4))) = q;
  }
  __syncthreads();

  int lane = t & 63;
  int w    = t >> 6;
  int lr   = lane & 15;
  int lkb  = (lane >> 4) * 16;

  f32x4 acc[2][8];
  #pragma unroll
  for (int m = 0; m < 2; ++m)
    #pragma unroll
    for (int n = 0; n < 8; ++n)
      acc[m][n] = (f32x4){0.f, 0.f, 0.f, 0.f};

  #pragma unroll
  for (int kk = 0; kk < 4; ++kk) {             // K = 4 x 32
    int kb = kk * 64 + lkb;
    bf16x8 af[2];
    #pragma unroll
    for (int m = 0; m < 2; ++m) {
      int row = m * 16 + lr;
      af[m] = *reinterpret_cast<const bf16x8*>(smem + row * 256 + (kb ^ ((row & 7) << 4)));
    }
    #pragma unroll
    for (int n = 0; n < 8; ++n) {
      int g = w * 8 + n;                       // 16-row group of B
      bf16x8 bf = *reinterpret_cast<const bf16x8*>(
          Bsw + ((size_t)(g * 4 + kk) * 64 + lane) * 8);   // coalesced 1KB/wave
      #pragma unroll
      for (int m = 0; m < 2; ++m)
        acc[m][n] = __builtin_amdgcn_mfma_f32_16x16x32_bf16(af[m], bf, acc[m][n], 0, 0, 0);
    }
  }
  __syncthreads();   // A-tile dead for ALL waves before epilogue reuses smem

  // ---- per-wave-private LDS transpose epilogue (wave-local, in-order DS) ----
  float* myT = reinterpret_cast<float*>(smem) + w * EPW;
  #pragma unroll
  for (int m = 0; m < 2; ++m) {
    int rbase = (lane >> 4) * 4;
    #pragma unroll
    for (int n = 0; n < 8; ++n) {
      #pragma unroll
      for (int r = 0; r < 4; ++r)
        myT[(rbase + r) * CPAD + n * 16 + lr] = acc[m][n][r];
    }
    #pragma unroll
    for (int it = 0; it < 8; ++it) {
      int idx = it * 64 + lane;
      int row = idx >> 5, c4 = idx & 31;
      f32x4 v = *reinterpret_cast<const f32x4*>(myT + row * CPAD + c4 * 4);
      int col = w * 128 + c4 * 4;
      if (col < NUM_CLASS) {   // only wave 7 tail masked; 1000 % 4 == 0
        *reinterpret_cast<f32x4*>(C + (size_t)(m0 + m * 16 + row) * NUM_CLASS + col) = v;
      }
    }
  }
}

extern "C" void kernel_launch(void* const* d_in, const int* in_sizes, int n_in,
                              void* d_out, int out_size, void* d_ws, size_t ws_size,
                              hipStream_t stream) {
  const float* pred_feat = (const float*)d_in[0];   // [1024,128]
  const int*   labels    = (const int*)d_in[1];     // [1024]
  const float* protos    = (const float*)d_in[2];   // [1000,128]
  const float* feat      = (const float*)d_in[3];   // [65536,128]
  float* out = (float*)d_out;                       // [65536,1000]

  unsigned short* protos_sw = (unsigned short*)d_ws;  // 256 KB fragment-swizzled

  proto_update_kernel<<<NPAD, 128, 0, stream>>>(pred_feat, labels, protos, protos_sw);
  gemm_sim_kernel<<<B_SIM / BM, TPB2, 0, stream>>>(feat, protos_sw, out);
}